// Round 3
// baseline (212.066 us; speedup 1.0000x reference)
//
#include <hip/hip_runtime.h>
#include <hip/hip_bf16.h>

#define N_NODES 50000
#define KNB 16
#define FDIM 128
#define HDIM 128
#define ALPHA 0.3f
#define BN_EPS 1e-3f

typedef __bf16 v8bf __attribute__((ext_vector_type(8)));
typedef float v4f __attribute__((ext_vector_type(4)));
typedef unsigned short ushort_t;

__device__ __forceinline__ float blo(unsigned int u) {
    union { float f; unsigned int i; } x; x.i = u << 16; return x.f;
}
__device__ __forceinline__ float bhi(unsigned int u) {
    union { float f; unsigned int i; } x; x.i = u & 0xffff0000u; return x.f;
}

__device__ __forceinline__ unsigned short f2bf(float f) {
    union { float f; unsigned int u; } x;
    x.f = f;
    unsigned int r = x.u + 0x7fffu + ((x.u >> 16) & 1u);  // RNE
    return (unsigned short)(r >> 16);
}

// packed f32x2 -> bf16x2 (RNE)
__device__ __forceinline__ unsigned int pk2(float a, float b) {
    __hip_bfloat162 h = __float22bfloat162_rn(make_float2(a, b));
    union { __hip_bfloat162 h; unsigned int u; } r; r.h = h; return r.u;
}

__device__ __forceinline__ float lrelu(float x) { return x > 0.f ? x : ALPHA * x; }

__device__ __forceinline__ v8bf load8f(const float* p) {
    float4 A = ((const float4*)p)[0];
    float4 B = ((const float4*)p)[1];
    union { v8bf v; unsigned int u[4]; } r;
    r.u[0] = pk2(A.x, A.y); r.u[1] = pk2(A.z, A.w);
    r.u[2] = pk2(B.x, B.y); r.u[3] = pk2(B.z, B.w);
    return r.v;
}

// ---------------------------------------------------------------------------
// Kernel 0: convert + transpose weights to bf16 once.
// WT layout (ushort): [0) WqT 128x128 | [16384) WkT | [32768) WvT | [49152) W1T 128x256
// ---------------------------------------------------------------------------
__global__ __launch_bounds__(256) void prep_kernel(
    const float* __restrict__ Wq, const float* __restrict__ Wk,
    const float* __restrict__ Wv, const float* __restrict__ W1,
    ushort_t* __restrict__ WT)
{
    const int idx = blockIdx.x * 256 + threadIdx.x;
    if (idx < 16384) {
        int k = idx >> 7, n = idx & 127;
        WT[n * 128 + k] = f2bf(Wq[idx]);
    } else if (idx < 32768) {
        int i = idx - 16384; int k = i >> 7, n = i & 127;
        WT[16384 + n * 128 + k] = f2bf(Wk[i]);
    } else if (idx < 49152) {
        int i = idx - 32768; int k = i >> 7, n = i & 127;
        WT[32768 + n * 128 + k] = f2bf(Wv[i]);
    } else if (idx < 81920) {
        int i = idx - 49152; int k = i >> 7, n = i & 127;  // k in [0,256)
        WT[49152 + n * 256 + k] = f2bf(W1[i]);
    }
}

// ---------------------------------------------------------------------------
// Kernel A (R2-proven — full-line store structure, unchanged):
// operand-swapped MFMA (D^T) + wave-private LDS staging + 1KB-linear
// dwordx4 copy-out. Single block does Q,K,V; B frags direct from L2-hot WT.
// ---------------------------------------------------------------------------
#define QSTRIDE 560   // bytes/row in Q staging tile (140 dwords: 2-way banks)
#define KVSTRIDE 528  // bytes/row in KV staging tile (132 dwords)
#define WTILE 18432   // per-wave LDS region (>= 32*560), 16B aligned

__global__ __launch_bounds__(256) void qkv_kernel(
    const float* __restrict__ E, const ushort_t* __restrict__ WT,
    const float* __restrict__ bq, const float* __restrict__ bk,
    const float* __restrict__ bv,
    float* __restrict__ Qo, ushort_t* __restrict__ KV)
{
    __shared__ char smem[4 * WTILE];

    const int tid  = threadIdx.x;
    const int wave = tid >> 6;
    const int lane = tid & 63;
    const int quad = lane >> 4;
    const int j    = lane & 15;
    const int row0 = blockIdx.x * 128 + wave * 32;

    char* const wbase = smem + wave * WTILE;

    const int ar0 = min(row0 + j,      N_NODES - 1);
    const int ar1 = min(row0 + 16 + j, N_NODES - 1);

    v8bf a0f[4], a1f[4];
#pragma unroll
    for (int ks = 0; ks < 4; ++ks) {
        const int k0 = ks * 32 + quad * 8;
        a0f[ks] = load8f(E + (size_t)ar0 * FDIM + k0);
        a1f[ks] = load8f(E + (size_t)ar1 * FDIM + k0);
    }

    const float* biases[3] = {bq, bk, bv};

    for (int w = 0; w < 3; ++w) {
        const ushort_t* __restrict__ Wsrc = WT + w * 16384;

        v4f acc[2][8];
#pragma unroll
        for (int rb = 0; rb < 2; ++rb)
#pragma unroll
            for (int c = 0; c < 8; ++c) acc[rb][c] = (v4f){0.f, 0.f, 0.f, 0.f};

#pragma unroll
        for (int ks = 0; ks < 4; ++ks) {
            const int k0 = ks * 32 + quad * 8;
            v8bf b[8];
#pragma unroll
            for (int c = 0; c < 8; ++c)
                b[c] = *(const v8bf*)(Wsrc + (c * 16 + j) * 128 + k0);
            // SWAPPED operands: D^T — lane (quad,j) holds rows row0+rb*16+j,
            // cols c*16+quad*4 .. +3 (4 consecutive columns).
#pragma unroll
            for (int c = 0; c < 8; ++c) {
                acc[0][c] = __builtin_amdgcn_mfma_f32_16x16x32_bf16(b[c], a0f[ks], acc[0][c], 0, 0, 0);
                acc[1][c] = __builtin_amdgcn_mfma_f32_16x16x32_bf16(b[c], a1f[ks], acc[1][c], 0, 0, 0);
            }
        }

        const float* __restrict__ bias = biases[w];

        if (w == 0) {
            // ---- Q: stage f32 tile (32 rows x 512B) then 1KB-linear stores
#pragma unroll
            for (int rb = 0; rb < 2; ++rb)
#pragma unroll
                for (int c = 0; c < 8; ++c) {
                    const float4 bb = ((const float4*)bias)[c * 4 + quad];
                    v4f v = acc[rb][c];
                    v[0] = lrelu(v[0] + bb.x); v[1] = lrelu(v[1] + bb.y);
                    v[2] = lrelu(v[2] + bb.z); v[3] = lrelu(v[3] + bb.w);
                    *(v4f*)(wbase + (rb * 16 + j) * QSTRIDE + (c * 16 + quad * 4) * 4) = v;
                }
#pragma unroll
            for (int t = 0; t < 16; ++t) {
                const int r  = 2 * t + (lane >> 5);
                const v4f v  = *(const v4f*)(wbase + r * QSTRIDE + (lane & 31) * 16);
                const int gr = row0 + r;
                if (gr < N_NODES)
                    *(v4f*)(Qo + (size_t)gr * HDIM + (lane & 31) * 4) = v;
            }
        } else {
            // ---- K (w=1) / V (w=2): pack bf16 into interleaved KV tile row
            const int voff = (w == 2) ? 256 : 0;  // V half at +256B in row
#pragma unroll
            for (int rb = 0; rb < 2; ++rb)
#pragma unroll
                for (int c = 0; c < 8; ++c) {
                    const float4 bb = ((const float4*)bias)[c * 4 + quad];
                    const v4f v = acc[rb][c];
                    uint2 u;
                    u.x = pk2(lrelu(v[0] + bb.x), lrelu(v[1] + bb.y));
                    u.y = pk2(lrelu(v[2] + bb.z), lrelu(v[3] + bb.w));
                    *(uint2*)(wbase + (rb * 16 + j) * KVSTRIDE + (c * 16 + quad * 4) * 2 + voff) = u;
                }
            if (w == 2) {
                // full 512B KV rows staged — 1KB-linear copy-out
#pragma unroll
                for (int t = 0; t < 16; ++t) {
                    const int r  = 2 * t + (lane >> 5);
                    const uint4 v = *(const uint4*)(wbase + r * KVSTRIDE + (lane & 31) * 16);
                    const int gr = row0 + r;
                    if (gr < N_NODES)   // guard: row 50000+ would smash WT in ws
                        *(uint4*)((char*)KV + (size_t)gr * 512 + (lane & 31) * 16) = v;
                }
            }
        }
    }
}

// ---------------------------------------------------------------------------
// Kernel B (R3 rewrite — group-per-neighbor):
// Old: 64-lane dot per neighbor => 16 x 6-stage shfl butterflies (~96 ds ops)
// + 32 single-dword gathers: DS-pipe bound (VALUBusy 49%, MfmaUtil 0,
// occ 75%, pinned 62 µs). New: 4 groups of 16 lanes, one neighbor per group
// per round (4 rounds); lane covers 8 elems via one uint4 (8 bf16) load.
// DS ops: 16 (scores, 4-stage within 16 lanes) + 4 (softmax xor16/32)
// + 16 (pooled xor16/32) = 36. VMEM: 12 wide insts. Same bytes moved.
// Same-wave q-read-before-pooled-write, grp0 stores. No LDS, no barriers.
// ---------------------------------------------------------------------------
#define DOT8(kp) (q0.x*blo(kp.x) + q0.y*bhi(kp.x) + q0.z*blo(kp.y) + q0.w*bhi(kp.y) \
                + q1.x*blo(kp.z) + q1.y*bhi(kp.z) + q1.z*blo(kp.w) + q1.w*bhi(kp.w))

__global__ __launch_bounds__(256) void attn_kernel(
    float* __restrict__ QP, const ushort_t* __restrict__ KV,
    const int* __restrict__ nbr)
{
    const int tid  = threadIdx.x;
    const int wave = tid >> 6;
    const int lane = tid & 63;
    const int grp  = lane >> 4;
    const int li   = lane & 15;
    const int node = __builtin_amdgcn_readfirstlane(blockIdx.x * 4 + wave);

    // per-lane q slice: elems li*8 .. li*8+7 (32B); row shared by all 4 groups
    const float4* qr = (const float4*)(QP + (size_t)node * HDIM + li * 8);
    const float4 q0 = qr[0];
    const float4 q1 = qr[1];

    const int* nb = nbr + node * KNB;   // uniform base -> scalar loads
    int nid0, nid1, nid2, nid3;         // this group's neighbor per round
#pragma unroll
    for (int t = 0; t < 4; ++t) {
        int i0 = nb[t * 4 + 0]; i0 = ((unsigned)i0 < (unsigned)N_NODES) ? i0 : 0;
        int i1 = nb[t * 4 + 1]; i1 = ((unsigned)i1 < (unsigned)N_NODES) ? i1 : 0;
        int i2 = nb[t * 4 + 2]; i2 = ((unsigned)i2 < (unsigned)N_NODES) ? i2 : 0;
        int i3 = nb[t * 4 + 3]; i3 = ((unsigned)i3 < (unsigned)N_NODES) ? i3 : 0;
        int v = i0;
        v = (grp == 1) ? i1 : v;
        v = (grp == 2) ? i2 : v;
        v = (grp == 3) ? i3 : v;
        if (t == 0) nid0 = v; else if (t == 1) nid1 = v;
        else if (t == 2) nid2 = v; else nid3 = v;
    }

    const char* kvb = (const char*)KV;
    const size_t lo16 = (size_t)(li * 16);

    // ---- scores: group g, round t -> neighbor t*4+g; 16-lane butterfly
    const uint4 k0 = *(const uint4*)(kvb + (size_t)nid0 * 512 + lo16);
    const uint4 k1 = *(const uint4*)(kvb + (size_t)nid1 * 512 + lo16);
    const uint4 k2 = *(const uint4*)(kvb + (size_t)nid2 * 512 + lo16);
    const uint4 k3 = *(const uint4*)(kvb + (size_t)nid3 * 512 + lo16);
    float s0 = DOT8(k0), s1 = DOT8(k1), s2 = DOT8(k2), s3 = DOT8(k3);
#pragma unroll
    for (int off = 1; off <= 8; off <<= 1) {
        s0 += __shfl_xor(s0, off, 64);
        s1 += __shfl_xor(s1, off, 64);
        s2 += __shfl_xor(s2, off, 64);
        s3 += __shfl_xor(s3, off, 64);
    }

    // ---- softmax across all 16 neighbors (4 local + cross-group xor16/32)
    float m = fmaxf(fmaxf(s0, s1), fmaxf(s2, s3));
    m = fmaxf(m, __shfl_xor(m, 16, 64));
    m = fmaxf(m, __shfl_xor(m, 32, 64));
    s0 = __expf(s0 - m); s1 = __expf(s1 - m);
    s2 = __expf(s2 - m); s3 = __expf(s3 - m);
    float ssum = s0 + s1 + s2 + s3;
    ssum += __shfl_xor(ssum, 16, 64);
    ssum += __shfl_xor(ssum, 32, 64);
    const float inv = 1.f / ssum;
    const float a0 = s0 * inv, a1 = s1 * inv, a2 = s2 * inv, a3 = s3 * inv;

    // ---- PV: group-partial over its 4 neighbors, then cross-group reduce
    const uint4 v0 = *(const uint4*)(kvb + (size_t)nid0 * 512 + 256 + lo16);
    const uint4 v1 = *(const uint4*)(kvb + (size_t)nid1 * 512 + 256 + lo16);
    const uint4 v2 = *(const uint4*)(kvb + (size_t)nid2 * 512 + 256 + lo16);
    const uint4 v3 = *(const uint4*)(kvb + (size_t)nid3 * 512 + 256 + lo16);

    float p0 = a0 * blo(v0.x) + a1 * blo(v1.x) + a2 * blo(v2.x) + a3 * blo(v3.x);
    float p1 = a0 * bhi(v0.x) + a1 * bhi(v1.x) + a2 * bhi(v2.x) + a3 * bhi(v3.x);
    float p2 = a0 * blo(v0.y) + a1 * blo(v1.y) + a2 * blo(v2.y) + a3 * blo(v3.y);
    float p3 = a0 * bhi(v0.y) + a1 * bhi(v1.y) + a2 * bhi(v2.y) + a3 * bhi(v3.y);
    float p4 = a0 * blo(v0.z) + a1 * blo(v1.z) + a2 * blo(v2.z) + a3 * blo(v3.z);
    float p5 = a0 * bhi(v0.z) + a1 * bhi(v1.z) + a2 * bhi(v2.z) + a3 * bhi(v3.z);
    float p6 = a0 * blo(v0.w) + a1 * blo(v1.w) + a2 * blo(v2.w) + a3 * blo(v3.w);
    float p7 = a0 * bhi(v0.w) + a1 * bhi(v1.w) + a2 * bhi(v2.w) + a3 * bhi(v3.w);

    p0 += __shfl_xor(p0, 16, 64); p1 += __shfl_xor(p1, 16, 64);
    p2 += __shfl_xor(p2, 16, 64); p3 += __shfl_xor(p3, 16, 64);
    p4 += __shfl_xor(p4, 16, 64); p5 += __shfl_xor(p5, 16, 64);
    p6 += __shfl_xor(p6, 16, 64); p7 += __shfl_xor(p7, 16, 64);
    p0 += __shfl_xor(p0, 32, 64); p1 += __shfl_xor(p1, 32, 64);
    p2 += __shfl_xor(p2, 32, 64); p3 += __shfl_xor(p3, 32, 64);
    p4 += __shfl_xor(p4, 32, 64); p5 += __shfl_xor(p5, 32, 64);
    p6 += __shfl_xor(p6, 32, 64); p7 += __shfl_xor(p7, 32, 64);

    if (grp == 0) {
        float4* out = (float4*)(QP + (size_t)node * HDIM + li * 8);
        out[0] = make_float4(p0, p1, p2, p3);
        out[1] = make_float4(p4, p5, p6, p7);
    }
}

// ---------------------------------------------------------------------------
// Kernel C (R3: swapped-operand MFMA + vectorized stores):
// out = BN(rownorm(lrelu([E,pooled]@W1+b1))). LDS W-staging kept (R1 proved
// removing it costs ~18 µs). D^T layout: lane (quad,j) holds rows rb*16+j,
// cols c*16+quad*4..+3 => 16B v4f stores (64B/row segments) instead of 4B
// scalars, and rownorm reduce is 2 shuffle stages (xor16/32) instead of 4.
// The barrier at the end of half=1 orders pooled reads before epilogue
// writes within a block; blocks touch only their own rows (R0-proven).
// ---------------------------------------------------------------------------
__global__ __launch_bounds__(256) void out_kernel(
    const float* __restrict__ E, const ushort_t* __restrict__ W1T,
    const float* __restrict__ b1,
    const float* __restrict__ gamma, const float* __restrict__ beta,
    const float* __restrict__ mmean, const float* __restrict__ mvar,
    float* __restrict__ OutP)   // pooled (in) + out (result)
{
    __shared__ ushort_t sW[128 * 136];

    const int tid  = threadIdx.x;
    const int wave = tid >> 6;
    const int lane = tid & 63;
    const int quad = lane >> 4;
    const int j    = lane & 15;
    const int row0 = blockIdx.x * 128 + wave * 32;

    const int ar0 = min(row0 + j,      N_NODES - 1);
    const int ar1 = min(row0 + 16 + j, N_NODES - 1);

    v4f acc[2][8];
#pragma unroll
    for (int rb = 0; rb < 2; ++rb)
#pragma unroll
        for (int c = 0; c < 8; ++c) acc[rb][c] = (v4f){0.f, 0.f, 0.f, 0.f};

    for (int half = 0; half < 2; ++half) {
        for (int i = tid; i < 2048; i += 256) {
            int n = i >> 4, kc = i & 15;
            *(uint4*)(&sW[n * 136 + kc * 8]) =
                *(const uint4*)(W1T + n * 256 + half * 128 + kc * 8);
        }
        __syncthreads();

        const float* Abase = (half == 0) ? E : (const float*)OutP;
#pragma unroll
        for (int ks = 0; ks < 4; ++ks) {
            const int k0 = ks * 32 + quad * 8;
            v8bf a0 = load8f(Abase + (size_t)ar0 * 128 + k0);
            v8bf a1 = load8f(Abase + (size_t)ar1 * 128 + k0);
            v8bf b[8];
#pragma unroll
            for (int c = 0; c < 8; ++c)
                b[c] = *(const v8bf*)(&sW[(c * 16 + j) * 136 + k0]);
            // SWAPPED operands: D^T (lane (quad,j) -> row rb*16+j, cols c*16+quad*4..+3)
#pragma unroll
            for (int c = 0; c < 8; ++c) {
                acc[0][c] = __builtin_amdgcn_mfma_f32_16x16x32_bf16(b[c], a0, acc[0][c], 0, 0, 0);
                acc[1][c] = __builtin_amdgcn_mfma_f32_16x16x32_bf16(b[c], a1, acc[1][c], 0, 0, 0);
            }
        }
        __syncthreads();   // orders pooled reads before epilogue writes
    }

    // 1) bias + lrelu
#pragma unroll
    for (int c = 0; c < 8; ++c) {
        const float4 bb = ((const float4*)b1)[c * 4 + quad];
#pragma unroll
        for (int rb = 0; rb < 2; ++rb) {
            acc[rb][c][0] = lrelu(acc[rb][c][0] + bb.x);
            acc[rb][c][1] = lrelu(acc[rb][c][1] + bb.y);
            acc[rb][c][2] = lrelu(acc[rb][c][2] + bb.z);
            acc[rb][c][3] = lrelu(acc[rb][c][3] + bb.w);
        }
    }

    // 2) row norms (row = rb*16 + j): quad-partials, reduce over xor16/32
    float ss0 = 0.f, ss1 = 0.f;
#pragma unroll
    for (int c = 0; c < 8; ++c)
#pragma unroll
        for (int i = 0; i < 4; ++i) {
            ss0 += acc[0][c][i] * acc[0][c][i];
            ss1 += acc[1][c][i] * acc[1][c][i];
        }
    ss0 += __shfl_xor(ss0, 16, 64); ss1 += __shfl_xor(ss1, 16, 64);
    ss0 += __shfl_xor(ss0, 32, 64); ss1 += __shfl_xor(ss1, 32, 64);
    const float inv0 = 1.f / (sqrtf(ss0) + 1e-6f);
    const float inv1 = 1.f / (sqrtf(ss1) + 1e-6f);

    // 3) BN + 16B vector stores
    const int r0w = row0 + j;
    const int r1w = row0 + 16 + j;
#pragma unroll
    for (int c = 0; c < 8; ++c) {
        const float4 g4 = ((const float4*)gamma)[c * 4 + quad];
        const float4 vv = ((const float4*)mvar )[c * 4 + quad];
        const float4 be = ((const float4*)beta )[c * 4 + quad];
        const float4 mm = ((const float4*)mmean)[c * 4 + quad];
        v4f sc4, sh4;
        sc4[0] = g4.x * rsqrtf(vv.x + BN_EPS); sh4[0] = be.x - mm.x * sc4[0];
        sc4[1] = g4.y * rsqrtf(vv.y + BN_EPS); sh4[1] = be.y - mm.y * sc4[1];
        sc4[2] = g4.z * rsqrtf(vv.z + BN_EPS); sh4[2] = be.z - mm.z * sc4[2];
        sc4[3] = g4.w * rsqrtf(vv.w + BN_EPS); sh4[3] = be.w - mm.w * sc4[3];
        const int colb = c * 16 + quad * 4;
        if (r0w < N_NODES) {
            v4f o;
#pragma unroll
            for (int i = 0; i < 4; ++i) o[i] = acc[0][c][i] * inv0 * sc4[i] + sh4[i];
            *(v4f*)(OutP + (size_t)r0w * HDIM + colb) = o;
        }
        if (r1w < N_NODES) {
            v4f o;
#pragma unroll
            for (int i = 0; i < 4; ++i) o[i] = acc[1][c][i] * inv1 * sc4[i] + sh4[i];
            *(v4f*)(OutP + (size_t)r1w * HDIM + colb) = o;
        }
    }
}

extern "C" void kernel_launch(void* const* d_in, const int* in_sizes, int n_in,
                              void* d_out, int out_size, void* d_ws, size_t ws_size,
                              hipStream_t stream)
{
    const float* E     = (const float*)d_in[0];
    const int*   nbr   = (const int*)d_in[2];
    const float* Wq    = (const float*)d_in[3];
    const float* bq    = (const float*)d_in[4];
    const float* Wk    = (const float*)d_in[5];
    const float* bk    = (const float*)d_in[6];
    const float* Wv    = (const float*)d_in[7];
    const float* bv    = (const float*)d_in[8];
    const float* W1    = (const float*)d_in[9];
    const float* b1    = (const float*)d_in[10];
    const float* gam   = (const float*)d_in[11];
    const float* bet   = (const float*)d_in[12];
    const float* mmean = (const float*)d_in[13];
    const float* mvar  = (const float*)d_in[14];

    // ws: KV interleaved bf16 (25.6 MB) + WT bf16 (160 KB) = 25.76 MB total
    // (PROVEN budget — R7's 38.56 MB overflowed d_ws and corrupted the
    // harness's pristine buffers). Q (f32) then pooled (f32) share d_out.
    ushort_t* KV = (ushort_t*)d_ws;
    ushort_t* WT = KV + (size_t)N_NODES * 256;
    float* QP = (float*)d_out;

    const int gridA = (N_NODES + 127) / 128;  // 391
    prep_kernel<<<320, 256, 0, stream>>>(Wq, Wk, Wv, W1, WT);
    qkv_kernel<<<gridA, 256, 0, stream>>>(E, WT, bq, bk, bv, QP, KV);
    attn_kernel<<<N_NODES / 4, 256, 0, stream>>>(QP, KV, nbr);
    out_kernel<<<gridA, 256, 0, stream>>>(E, WT + 49152, b1, gam, bet, mmean, mvar, QP);
}